// Round 3
// baseline (186.911 us; speedup 1.0000x reference)
//
#include <hip/hip_runtime.h>
#include <cstdint>
#include <cstddef>

typedef unsigned short u16;
typedef u16   u16x8  __attribute__((ext_vector_type(8)));
typedef __bf16 bf16x8 __attribute__((ext_vector_type(8)));
typedef float f32x4  __attribute__((ext_vector_type(4)));

__device__ __forceinline__ float bf2f(u16 v) {
  unsigned int u = ((unsigned int)v) << 16;
  return __builtin_bit_cast(float, u);
}
__device__ __forceinline__ u16 f2bf(float f) {
  unsigned int x = __builtin_bit_cast(unsigned int, f);
  x += 0x7fffu + ((x >> 16) & 1u);   // RNE
  return (u16)(x >> 16);
}

// ---------------------------------------------------------------------------
// Kernel 0: transpose+convert W21 [1024,512] f32 and W22 [1024,512] f32 into
// bf16 Wt [1024(n),1024(k)]:
//   Wt[n][k] = W21[k][n]  (n<512) ; W22[k][n-512] (n>=512)
// ---------------------------------------------------------------------------
__global__ __launch_bounds__(256) void k_tr(const float* __restrict__ W21,
                                            const float* __restrict__ W22,
                                            u16* __restrict__ Wt) {
  __shared__ u16 s[64][65];
  const int b   = blockIdx.x;        // 256 blocks
  const int mat = b >> 7;            // 0: W21, 1: W22
  const int tt  = b & 127;
  const int k0  = (tt >> 3) * 64;    // 16 k-tiles
  const int n0  = (tt & 7) * 64;     // 8 n-tiles
  const float* W = mat ? W22 : W21;
  const int tx = threadIdx.x & 63;
  const int ty = threadIdx.x >> 6;   // 0..3
#pragma unroll
  for (int i = 0; i < 16; ++i) {
    int r = i * 4 + ty;
    s[r][tx] = f2bf(W[(size_t)(k0 + r) * 512 + n0 + tx]);   // coalesced read
  }
  __syncthreads();
  const int nbase = mat * 512 + n0;
#pragma unroll
  for (int i = 0; i < 16; ++i) {
    int r = i * 4 + ty;
    Wt[(size_t)(nbase + r) * 1024 + k0 + tx] = s[tx][r];    // coalesced write
  }
}

// ---------------------------------------------------------------------------
// Kernel 1: h1 = relu(x @ W1 + b1)   f32 in -> bf16 [8192,1024]
// NOTE: reference uses RAW x here (x0 = x*std+mean is only the physical state)
// ---------------------------------------------------------------------------
__global__ __launch_bounds__(256) void k_h1(const float* __restrict__ x,
                                            const float* __restrict__ W1,
                                            const float* __restrict__ b1,
                                            u16* __restrict__ h1) {
  const int col = blockIdx.x * 256 + threadIdx.x;  // gridDim.x = 4
  const int row = blockIdx.y;
  const f32x4* xp = (const f32x4*)(x + (size_t)row * 8);
  f32x4 xa = xp[0], xb = xp[1];
  float acc = b1[col];
#pragma unroll
  for (int f = 0; f < 4; ++f) {
    acc = fmaf(xa[f], W1[f * 1024 + col], acc);
    acc = fmaf(xb[f], W1[(f + 4) * 1024 + col], acc);
  }
  h1[(size_t)row * 1024 + col] = f2bf(fmaxf(acc, 0.f));
}

// ---------------------------------------------------------------------------
// Kernel 2: X2 = relu(h1 @ [W21|W22] + [b21|b22])  -> bf16 [8192, 1024]
// MFMA 16x16x32 bf16. Block: 256 thr = 4 waves, tile 128x128, BK=32.
// A: h1 row-major bf16 [M,K].  B: Wt n-major bf16 [N,K].  bias f32.
// ---------------------------------------------------------------------------
__global__ __launch_bounds__(256) void k_gemm(const u16* __restrict__ A,
                                              const u16* __restrict__ Bt,
                                              const float* __restrict__ b21,
                                              const float* __restrict__ b22,
                                              u16* __restrict__ X2) {
  constexpr int K = 1024;
  constexpr int BK = 32;
  __shared__ u16 As[128 * BK];
  __shared__ u16 Bs[128 * BK];

  const int t    = threadIdx.x;
  const int row0 = blockIdx.y * 128;
  const int col0 = blockIdx.x * 128;
  const int w    = t >> 6;
  const int lane = t & 63;
  const int wr   = w >> 1, wc = w & 1;      // 2x2 wave grid, each wave 64x64
  const int lrow = lane & 15;
  const int lk   = (lane >> 4) * 8;

  f32x4 acc[4][4];
#pragma unroll
  for (int i = 0; i < 4; ++i)
#pragma unroll
    for (int j = 0; j < 4; ++j) acc[i][j] = f32x4{0.f, 0.f, 0.f, 0.f};

  // chunk scheme: 16B chunks; j<2 -> A tile (512 chunks), j>=2 -> B tile
  u16x8 ld[4];
#pragma unroll
  for (int j = 0; j < 4; ++j) {
    int c = (j * 256 + t) & 511;
    const u16* base = (j < 2) ? (A + (size_t)(row0 + (c >> 2)) * K)
                              : (Bt + (size_t)(col0 + (c >> 2)) * K);
    ld[j] = *(const u16x8*)(base + (c & 3) * 8);
  }

  for (int kt = 0; kt < K / BK; ++kt) {
#pragma unroll
    for (int j = 0; j < 4; ++j) {
      int c = (j * 256 + t) & 511;
      u16* dst = (j < 2) ? (As + c * 8) : (Bs + c * 8);
      *(u16x8*)dst = ld[j];
    }
    __syncthreads();
    if (kt + 1 < K / BK) {
#pragma unroll
      for (int j = 0; j < 4; ++j) {
        int c = (j * 256 + t) & 511;
        const u16* base = (j < 2) ? (A + (size_t)(row0 + (c >> 2)) * K)
                                  : (Bt + (size_t)(col0 + (c >> 2)) * K);
        ld[j] = *(const u16x8*)(base + (size_t)(kt + 1) * BK + (c & 3) * 8);
      }
    }
    bf16x8 af[4], bfr[4];
#pragma unroll
    for (int i = 0; i < 4; ++i)
      af[i] = __builtin_bit_cast(bf16x8,
          *(const u16x8*)(As + (wr * 64 + i * 16 + lrow) * BK + lk));
#pragma unroll
    for (int j = 0; j < 4; ++j)
      bfr[j] = __builtin_bit_cast(bf16x8,
          *(const u16x8*)(Bs + (wc * 64 + j * 16 + lrow) * BK + lk));
#pragma unroll
    for (int i = 0; i < 4; ++i)
#pragma unroll
      for (int j = 0; j < 4; ++j)
        acc[i][j] = __builtin_amdgcn_mfma_f32_16x16x32_bf16(af[i], bfr[j], acc[i][j], 0, 0, 0);
    __syncthreads();
  }

  // epilogue: D[row=(lane>>4)*4+r][col=lane&15], + bias, relu, bf16 store
#pragma unroll
  for (int j = 0; j < 4; ++j) {
    int col = col0 + wc * 64 + j * 16 + lrow;
    float bias = (col < 512) ? b21[col] : b22[col - 512];
#pragma unroll
    for (int i = 0; i < 4; ++i) {
      int rbase = row0 + wr * 64 + i * 16 + (lane >> 4) * 4;
#pragma unroll
      for (int rr = 0; rr < 4; ++rr) {
        float v = acc[i][j][rr] + bias;
        X2[(size_t)(rbase + rr) * 1024 + col] = f2bf(fmaxf(v, 0.f));
      }
    }
  }
}

// ---------------------------------------------------------------------------
// Kernel 3: heads (x31, x32) + barrier construction + rank-2 dual PGD QP
// One thread per batch row. f32 I/O except X2 (bf16).
// ---------------------------------------------------------------------------
__global__ __launch_bounds__(64) void k_qp(const float* __restrict__ x,
                                           const float* __restrict__ mean_,
                                           const float* __restrict__ std_,
                                           const u16* __restrict__ X2,
                                           const float* __restrict__ W31,
                                           const float* __restrict__ b31,
                                           const float* __restrict__ W32,
                                           const float* __restrict__ b32,
                                           const float* __restrict__ obstacles,
                                           float* __restrict__ out) {
  __shared__ float w31x[512], w31y[512], w32x[512], w32y[512];
  for (int i = threadIdx.x; i < 512; i += 64) {
    w31x[i] = W31[2 * i]; w31y[i] = W31[2 * i + 1];
    w32x[i] = W32[2 * i]; w32y[i] = W32[2 * i + 1];
  }
  __syncthreads();

  const int r = blockIdx.x * 64 + threadIdx.x;
  const u16x8* rowp = (const u16x8*)(X2 + (size_t)r * 1024);

  float a31x = 0.f, a31y = 0.f, a32x = 0.f, a32y = 0.f;
#pragma unroll 2
  for (int c = 0; c < 64; ++c) {             // x21 -> x31 head
    u16x8 v = rowp[c];
#pragma unroll
    for (int e = 0; e < 8; ++e) {
      float f = bf2f(v[e]); int k = c * 8 + e;
      a31x = fmaf(f, w31x[k], a31x);
      a31y = fmaf(f, w31y[k], a31y);
    }
  }
#pragma unroll 2
  for (int c = 0; c < 64; ++c) {             // x22 -> x32 head
    u16x8 v = rowp[64 + c];
#pragma unroll
    for (int e = 0; e < 8; ++e) {
      float f = bf2f(v[e]); int k = c * 8 + e;
      a32x = fmaf(f, w32x[k], a32x);
      a32y = fmaf(f, w32y[k], a32y);
    }
  }
  float p0  = a31x + b31[0];
  float p1v = a31y + b31[1];
  float pp1 = 4.f / (1.f + expf(-(a32x + b32[0])));
  float pp2 = 4.f / (1.f + expf(-(a32y + b32[1])));

  const f32x4* xp = (const f32x4*)(x + (size_t)r * 8);
  f32x4 xa = xp[0], xb = xp[1];
  float x0[6];
#pragma unroll
  for (int f = 0; f < 4; ++f) x0[f] = xa[f] * std_[f] + mean_[f];
  x0[4] = xb[0] * std_[4] + mean_[4];
  x0[5] = xb[1] * std_[5] + mean_[5];
  float px = x0[0], py = x0[1], th = x0[2], v = x0[3], ax = x0[4], ay = x0[5];
  float st = sinf(th), ct = cosf(th);
  float Lf2b = 2.f * v * v;

  float G0[9], G1[9], q[9];
  float s00 = 0.f, s01 = 0.f, s11 = 0.f;
#pragma unroll
  for (int m = 0; m < 9; ++m) {
    float ox, oy, orad;
    if (m < 8) {
      ox = obstacles[m * 3]; oy = obstacles[m * 3 + 1]; orad = obstacles[m * 3 + 2];
    } else { ox = ax; oy = ay; orad = 0.5f; }
    float R  = 0.6f + orad;                  // AGENT_RADIUS + orad + SAFETY
    float dx = px - ox, dy = py - oy;
    float bar  = dx * dx + dy * dy - R * R;
    float dct  = dx * ct + dy * st;
    float bdot = 2.f * v * dct;
    float g0 = 2.f * v * (dx * st - dy * ct);   // -LgLfbu1
    float g1 = -2.f * dct;                      // -LgLfbu2
    float h  = Lf2b + (pp1 + pp2) * bdot + pp1 * pp2 * bar;
    G0[m] = g0; G1[m] = g1;
    q[m] = g0 * p0 + g1 * p1v + h;
    s00 += g0 * g0; s01 += g0 * g1; s11 += g1 * g1;
  }
  // ||G G^T||_F == ||G^T G||_F  (rank-2)
  float L = sqrtf(s00 * s00 + 2.f * s01 * s01 + s11 * s11) + 1e-6f;
  float alpha = 1.f / L;

  float lam[9];
#pragma unroll
  for (int m = 0; m < 9; ++m) lam[m] = 0.f;
  for (int it = 0; it < 300; ++it) {
    float t0 = 0.f, t1 = 0.f;
#pragma unroll
    for (int m = 0; m < 9; ++m) { t0 = fmaf(G0[m], lam[m], t0); t1 = fmaf(G1[m], lam[m], t1); }
#pragma unroll
    for (int m = 0; m < 9; ++m) {
      float g = fmaf(G0[m], t0, fmaf(G1[m], t1, q[m]));
      lam[m] = fmaxf(fmaf(-alpha, g, lam[m]), 0.f);
    }
  }
  float u0 = -p0, u1 = -p1v;
#pragma unroll
  for (int m = 0; m < 9; ++m) { u0 = fmaf(-G0[m], lam[m], u0); u1 = fmaf(-G1[m], lam[m], u1); }
  out[2 * (size_t)r]     = u0;
  out[2 * (size_t)r + 1] = u1;
}

// ---------------------------------------------------------------------------
extern "C" void kernel_launch(void* const* d_in, const int* in_sizes, int n_in,
                              void* d_out, int out_size, void* d_ws, size_t ws_size,
                              hipStream_t stream) {
  const float* x    = (const float*)d_in[0];
  const float* mean_= (const float*)d_in[1];
  const float* std_ = (const float*)d_in[2];
  const float* W1   = (const float*)d_in[3];
  const float* b1   = (const float*)d_in[4];
  const float* W21  = (const float*)d_in[5];
  const float* b21  = (const float*)d_in[6];
  const float* W22  = (const float*)d_in[7];
  const float* b22  = (const float*)d_in[8];
  // d_in[9],[10] = W23,b23 : dead code in reference (x33 unused)
  const float* W31  = (const float*)d_in[11];
  const float* b31  = (const float*)d_in[12];
  const float* W32  = (const float*)d_in[13];
  const float* b32  = (const float*)d_in[14];
  // d_in[15],[16] = W33,b33 : dead code
  const float* obst = (const float*)d_in[17];
  float* out = (float*)d_out;

  char* ws = (char*)d_ws;
  u16* Wt = (u16*)ws;                                  // 1024*1024*2  = 2 MB
  u16* h1 = (u16*)(ws + (size_t)(1 << 21));            // 8192*1024*2  = 16 MB
  u16* X2 = (u16*)(ws + (size_t)(1 << 21) + (size_t)(1 << 24)); // 16 MB

  k_tr  <<<256, 256, 0, stream>>>(W21, W22, Wt);
  k_h1  <<<dim3(4, 8192), 256, 0, stream>>>(x, W1, b1, h1);
  k_gemm<<<dim3(8, 64), 256, 0, stream>>>(h1, Wt, b21, b22, X2);
  k_qp  <<<128, 64, 0, stream>>>(x, mean_, std_, X2, W31, b31, W32, b32, obst, out);
}

// Round 4
// 172.462 us; speedup vs baseline: 1.0838x; 1.0838x over previous
//
#include <hip/hip_runtime.h>
#include <cstdint>
#include <cstddef>

typedef unsigned short u16;
typedef u16   u16x8  __attribute__((ext_vector_type(8)));
typedef u16   u16x4  __attribute__((ext_vector_type(4)));
typedef __bf16 bf16x8 __attribute__((ext_vector_type(8)));
typedef float f32x4  __attribute__((ext_vector_type(4)));
typedef float f32x2  __attribute__((ext_vector_type(2)));

__device__ __forceinline__ float bf2f(u16 v) {
  unsigned int u = ((unsigned int)v) << 16;
  return __builtin_bit_cast(float, u);
}
__device__ __forceinline__ u16 f2bf(float f) {
  unsigned int x = __builtin_bit_cast(unsigned int, f);
  x += 0x7fffu + ((x >> 16) & 1u);   // RNE
  return (u16)(x >> 16);
}

// async global->LDS, 16B per lane. LDS dest must be wave-uniform base + lane*16.
__device__ __forceinline__ void gld_lds16(const u16* g, u16* l) {
  __builtin_amdgcn_global_load_lds(
      (const __attribute__((address_space(1))) unsigned int*)g,
      (__attribute__((address_space(3))) unsigned int*)l, 16, 0, 0);
}

// ---------------------------------------------------------------------------
// Kernel 0: transpose+convert W21/W22 [1024,512] f32 -> bf16 Wt [1024(n),1024(k)]
// ---------------------------------------------------------------------------
__global__ __launch_bounds__(256) void k_tr(const float* __restrict__ W21,
                                            const float* __restrict__ W22,
                                            u16* __restrict__ Wt) {
  __shared__ u16 s[64][65];
  const int b   = blockIdx.x;        // 256 blocks
  const int mat = b >> 7;
  const int tt  = b & 127;
  const int k0  = (tt >> 3) * 64;
  const int n0  = (tt & 7) * 64;
  const float* W = mat ? W22 : W21;
  const int tx = threadIdx.x & 63;
  const int ty = threadIdx.x >> 6;
#pragma unroll
  for (int i = 0; i < 16; ++i) {
    int r = i * 4 + ty;
    s[r][tx] = f2bf(W[(size_t)(k0 + r) * 512 + n0 + tx]);
  }
  __syncthreads();
  const int nbase = mat * 512 + n0;
#pragma unroll
  for (int i = 0; i < 16; ++i) {
    int r = i * 4 + ty;
    Wt[(size_t)(nbase + r) * 1024 + k0 + tx] = s[tx][r];
  }
}

// ---------------------------------------------------------------------------
// Kernel 1: h1 = relu(x @ W1 + b1)  (RAW x) -> bf16 [8192,1024]
// 8192 blocks x 256 thr, 4 cols/thread.
// ---------------------------------------------------------------------------
__global__ __launch_bounds__(256) void k_h1(const float* __restrict__ x,
                                            const float* __restrict__ W1,
                                            const float* __restrict__ b1,
                                            u16* __restrict__ h1) {
  const int row = blockIdx.x;
  const int c4  = threadIdx.x * 4;
  const float* xr = x + (size_t)row * 8;
  f32x4 acc = *(const f32x4*)(b1 + c4);
#pragma unroll
  for (int f = 0; f < 8; ++f) {
    float xv = xr[f];                       // row-uniform -> scalar loads
    f32x4 wv = *(const f32x4*)(W1 + f * 1024 + c4);
#pragma unroll
    for (int e = 0; e < 4; ++e) acc[e] = fmaf(xv, wv[e], acc[e]);
  }
  u16x4 o;
#pragma unroll
  for (int e = 0; e < 4; ++e) o[e] = f2bf(fmaxf(acc[e], 0.f));
  *(u16x4*)(h1 + (size_t)row * 1024 + c4) = o;
}

// ---------------------------------------------------------------------------
// Kernel 2: X2 = relu(h1 @ [W21|W22] + bias) -> bf16 [8192,1024]
// MFMA 16x16x32, 128x128 tile, BK=32, async global_load_lds staging (16B).
// ---------------------------------------------------------------------------
__global__ __launch_bounds__(256) void k_gemm(const u16* __restrict__ A,
                                              const u16* __restrict__ Bt,
                                              const float* __restrict__ b21,
                                              const float* __restrict__ b22,
                                              u16* __restrict__ X2) {
  constexpr int K = 1024;
  constexpr int BK = 32;
  __shared__ u16 As[128 * BK];
  __shared__ u16 Bs[128 * BK];

  const int t    = threadIdx.x;
  const int row0 = blockIdx.y * 128;
  const int col0 = blockIdx.x * 128;
  const int w    = t >> 6;
  const int lane = t & 63;
  const int wr   = w >> 1, wc = w & 1;
  const int lrow = lane & 15;
  const int lk   = (lane >> 4) * 8;

  // chunk c encodes (row = c>>2, 16B-kchunk = c&3); LDS is row-major [128][32]
  const int cA0 = t, cA1 = 256 + t;    // A chunks
  const int cB0 = t, cB1 = 256 + t;    // B chunks
  const u16* gA0 = A  + (size_t)(row0 + (cA0 >> 2)) * K + (cA0 & 3) * 8;
  const u16* gA1 = A  + (size_t)(row0 + (cA1 >> 2)) * K + (cA1 & 3) * 8;
  const u16* gB0 = Bt + (size_t)(col0 + (cB0 >> 2)) * K + (cB0 & 3) * 8;
  const u16* gB1 = Bt + (size_t)(col0 + (cB1 >> 2)) * K + (cB1 & 3) * 8;
  u16* lA0 = As + cA0 * 8;
  u16* lA1 = As + cA1 * 8;
  u16* lB0 = Bs + cB0 * 8;
  u16* lB1 = Bs + cB1 * 8;

  f32x4 acc[4][4];
#pragma unroll
  for (int i = 0; i < 4; ++i)
#pragma unroll
    for (int j = 0; j < 4; ++j) acc[i][j] = f32x4{0.f, 0.f, 0.f, 0.f};

  for (int kt = 0; kt < K / BK; ++kt) {
    gld_lds16(gA0, lA0);
    gld_lds16(gA1, lA1);
    gld_lds16(gB0, lB0);
    gld_lds16(gB1, lB1);
    gA0 += BK; gA1 += BK; gB0 += BK; gB1 += BK;
    __syncthreads();            // drains vmcnt -> LDS valid

    bf16x8 af[4], bfr[4];
#pragma unroll
    for (int i = 0; i < 4; ++i)
      af[i] = __builtin_bit_cast(bf16x8,
          *(const u16x8*)(As + (wr * 64 + i * 16 + lrow) * BK + lk));
#pragma unroll
    for (int j = 0; j < 4; ++j)
      bfr[j] = __builtin_bit_cast(bf16x8,
          *(const u16x8*)(Bs + (wc * 64 + j * 16 + lrow) * BK + lk));
#pragma unroll
    for (int i = 0; i < 4; ++i)
#pragma unroll
      for (int j = 0; j < 4; ++j)
        acc[i][j] = __builtin_amdgcn_mfma_f32_16x16x32_bf16(af[i], bfr[j], acc[i][j], 0, 0, 0);
    __syncthreads();            // protect LDS before next iteration's loads
  }

#pragma unroll
  for (int j = 0; j < 4; ++j) {
    int col = col0 + wc * 64 + j * 16 + lrow;
    float bias = (col < 512) ? b21[col] : b22[col - 512];
#pragma unroll
    for (int i = 0; i < 4; ++i) {
      int rbase = row0 + wr * 64 + i * 16 + (lane >> 4) * 4;
#pragma unroll
      for (int rr = 0; rr < 4; ++rr) {
        float v = acc[i][j][rr] + bias;
        X2[(size_t)(rbase + rr) * 1024 + col] = f2bf(fmaxf(v, 0.f));
      }
    }
  }
}

// ---------------------------------------------------------------------------
// Kernel 3: head dots. One wave per row; coalesced X2 reads; butterfly reduce.
// head[r] = { x21.w31x, x21.w31y, x22.w32x, x22.w32y }  (pre-bias)
// ---------------------------------------------------------------------------
__global__ __launch_bounds__(256) void k_head(const u16* __restrict__ X2,
                                              const float* __restrict__ W31,
                                              const float* __restrict__ W32,
                                              float* __restrict__ head) {
  const int wv   = threadIdx.x >> 6;
  const int lane = threadIdx.x & 63;
  const int r    = blockIdx.x * 4 + wv;
  const u16* row = X2 + (size_t)r * 1024;

  u16x8 v0 = *(const u16x8*)(row + lane * 8);          // x21 half: k = lane*8..+7
  u16x8 v1 = *(const u16x8*)(row + 512 + lane * 8);    // x22 half
  const f32x4* w31p = (const f32x4*)(W31 + lane * 16); // (wx,wy) pairs
  const f32x4* w32p = (const f32x4*)(W32 + lane * 16);

  float a0x = 0.f, a0y = 0.f, a1x = 0.f, a1y = 0.f;
#pragma unroll
  for (int i = 0; i < 4; ++i) {
    f32x4 wa = w31p[i];
    float e0 = bf2f(v0[2 * i]), e1 = bf2f(v0[2 * i + 1]);
    a0x = fmaf(e0, wa[0], a0x); a0y = fmaf(e0, wa[1], a0y);
    a0x = fmaf(e1, wa[2], a0x); a0y = fmaf(e1, wa[3], a0y);
    f32x4 wb = w32p[i];
    float f0 = bf2f(v1[2 * i]), f1 = bf2f(v1[2 * i + 1]);
    a1x = fmaf(f0, wb[0], a1x); a1y = fmaf(f0, wb[1], a1y);
    a1x = fmaf(f1, wb[2], a1x); a1y = fmaf(f1, wb[3], a1y);
  }
#pragma unroll
  for (int m = 32; m >= 1; m >>= 1) {
    a0x += __shfl_xor(a0x, m, 64);
    a0y += __shfl_xor(a0y, m, 64);
    a1x += __shfl_xor(a1x, m, 64);
    a1y += __shfl_xor(a1y, m, 64);
  }
  if (lane == 0)
    *(f32x4*)(head + 4 * (size_t)r) = f32x4{a0x, a0y, a1x, a1y};
}

// ---------------------------------------------------------------------------
// Kernel 4: rank-2 dual PGD QP. One thread per row; heads precomputed.
// ---------------------------------------------------------------------------
__global__ __launch_bounds__(64) void k_qp(const float* __restrict__ x,
                                           const float* __restrict__ mean_,
                                           const float* __restrict__ std_,
                                           const float* __restrict__ head,
                                           const float* __restrict__ b31,
                                           const float* __restrict__ b32,
                                           const float* __restrict__ obstacles,
                                           float* __restrict__ out) {
  const int r = blockIdx.x * 64 + threadIdx.x;
  f32x4 hd = *(const f32x4*)(head + 4 * (size_t)r);
  float p0  = hd[0] + b31[0];
  float p1v = hd[1] + b31[1];
  float pp1 = 4.f / (1.f + expf(-(hd[2] + b32[0])));
  float pp2 = 4.f / (1.f + expf(-(hd[3] + b32[1])));

  const f32x4* xp = (const f32x4*)(x + (size_t)r * 8);
  f32x4 xa = xp[0], xb = xp[1];
  float px = xa[0] * std_[0] + mean_[0];
  float py = xa[1] * std_[1] + mean_[1];
  float th = xa[2] * std_[2] + mean_[2];
  float v  = xa[3] * std_[3] + mean_[3];
  float ax = xb[0] * std_[4] + mean_[4];
  float ay = xb[1] * std_[5] + mean_[5];
  float st = sinf(th), ct = cosf(th);
  float Lf2b = 2.f * v * v;

  float G0[9], G1[9], q[9];
  float s00 = 0.f, s01 = 0.f, s11 = 0.f;
#pragma unroll
  for (int m = 0; m < 9; ++m) {
    float ox, oy, orad;
    if (m < 8) {
      ox = obstacles[m * 3]; oy = obstacles[m * 3 + 1]; orad = obstacles[m * 3 + 2];
    } else { ox = ax; oy = ay; orad = 0.5f; }
    float R  = 0.6f + orad;                  // AGENT_RADIUS + orad + SAFETY
    float dx = px - ox, dy = py - oy;
    float bar  = dx * dx + dy * dy - R * R;
    float dct  = dx * ct + dy * st;
    float bdot = 2.f * v * dct;
    float g0 = 2.f * v * (dx * st - dy * ct);   // -LgLfbu1
    float g1 = -2.f * dct;                      // -LgLfbu2
    float h  = Lf2b + (pp1 + pp2) * bdot + pp1 * pp2 * bar;
    G0[m] = g0; G1[m] = g1;
    q[m] = g0 * p0 + g1 * p1v + h;
    s00 += g0 * g0; s01 += g0 * g1; s11 += g1 * g1;
  }
  float L = sqrtf(s00 * s00 + 2.f * s01 * s01 + s11 * s11) + 1e-6f;
  float alpha = 1.f / L;

  float lam[9];
#pragma unroll
  for (int m = 0; m < 9; ++m) lam[m] = 0.f;
  for (int it = 0; it < 300; ++it) {
    float pr0[9], pr1[9];
#pragma unroll
    for (int m = 0; m < 9; ++m) { pr0[m] = G0[m] * lam[m]; pr1[m] = G1[m] * lam[m]; }
    // tree-sum: dependency depth 4 instead of 9
    float t0 = (((pr0[0] + pr0[1]) + (pr0[2] + pr0[3])) +
                ((pr0[4] + pr0[5]) + (pr0[6] + pr0[7]))) + pr0[8];
    float t1 = (((pr1[0] + pr1[1]) + (pr1[2] + pr1[3])) +
                ((pr1[4] + pr1[5]) + (pr1[6] + pr1[7]))) + pr1[8];
#pragma unroll
    for (int m = 0; m < 9; ++m) {
      float g = fmaf(G0[m], t0, fmaf(G1[m], t1, q[m]));
      lam[m] = fmaxf(fmaf(-alpha, g, lam[m]), 0.f);
    }
  }
  float u0 = -p0, u1 = -p1v;
#pragma unroll
  for (int m = 0; m < 9; ++m) { u0 = fmaf(-G0[m], lam[m], u0); u1 = fmaf(-G1[m], lam[m], u1); }
  *(f32x2*)(out + 2 * (size_t)r) = f32x2{u0, u1};
}

// ---------------------------------------------------------------------------
extern "C" void kernel_launch(void* const* d_in, const int* in_sizes, int n_in,
                              void* d_out, int out_size, void* d_ws, size_t ws_size,
                              hipStream_t stream) {
  const float* x    = (const float*)d_in[0];
  const float* mean_= (const float*)d_in[1];
  const float* std_ = (const float*)d_in[2];
  const float* W1   = (const float*)d_in[3];
  const float* b1   = (const float*)d_in[4];
  const float* W21  = (const float*)d_in[5];
  const float* b21  = (const float*)d_in[6];
  const float* W22  = (const float*)d_in[7];
  const float* b22  = (const float*)d_in[8];
  // d_in[9],[10] = W23,b23 : dead code in reference (x33 unused)
  const float* W31  = (const float*)d_in[11];
  const float* b31  = (const float*)d_in[12];
  const float* W32  = (const float*)d_in[13];
  const float* b32  = (const float*)d_in[14];
  // d_in[15],[16] = W33,b33 : dead code
  const float* obst = (const float*)d_in[17];
  float* out = (float*)d_out;

  char* ws = (char*)d_ws;
  u16*   Wt   = (u16*)ws;                                             // 2 MB
  u16*   h1   = (u16*)(ws + (size_t)(1 << 21));                       // 16 MB
  u16*   X2   = (u16*)(ws + (size_t)(1 << 21) + (size_t)(1 << 24));   // 16 MB
  float* head = (float*)(ws + (size_t)(1 << 21) + 2 * (size_t)(1 << 24)); // 128 KB

  k_tr  <<<256, 256, 0, stream>>>(W21, W22, Wt);
  k_h1  <<<8192, 256, 0, stream>>>(x, W1, b1, h1);
  k_gemm<<<dim3(8, 64), 256, 0, stream>>>(h1, Wt, b21, b22, X2);
  k_head<<<2048, 256, 0, stream>>>(X2, W31, W32, head);
  k_qp  <<<128, 64, 0, stream>>>(x, mean_, std_, head, b31, b32, obst, out);
}

// Round 5
// 171.031 us; speedup vs baseline: 1.0929x; 1.0084x over previous
//
#include <hip/hip_runtime.h>
#include <cstdint>
#include <cstddef>

typedef unsigned short u16;
typedef u16   u16x8  __attribute__((ext_vector_type(8)));
typedef u16   u16x4  __attribute__((ext_vector_type(4)));
typedef __bf16 bf16x8 __attribute__((ext_vector_type(8)));
typedef float f32x4  __attribute__((ext_vector_type(4)));
typedef float f32x2  __attribute__((ext_vector_type(2)));

__device__ __forceinline__ float bf2f(u16 v) {
  unsigned int u = ((unsigned int)v) << 16;
  return __builtin_bit_cast(float, u);
}
__device__ __forceinline__ u16 f2bf(float f) {
  unsigned int x = __builtin_bit_cast(unsigned int, f);
  x += 0x7fffu + ((x >> 16) & 1u);   // RNE
  return (u16)(x >> 16);
}

// ---------------------------------------------------------------------------
// Kernel 0: transpose+convert W21/W22 [1024,512] f32 -> bf16 Wt [1024(n),1024(k)]
// ---------------------------------------------------------------------------
__global__ __launch_bounds__(256) void k_tr(const float* __restrict__ W21,
                                            const float* __restrict__ W22,
                                            u16* __restrict__ Wt) {
  __shared__ u16 s[64][65];
  const int b   = blockIdx.x;        // 256 blocks
  const int mat = b >> 7;
  const int tt  = b & 127;
  const int k0  = (tt >> 3) * 64;
  const int n0  = (tt & 7) * 64;
  const float* W = mat ? W22 : W21;
  const int tx = threadIdx.x & 63;
  const int ty = threadIdx.x >> 6;
#pragma unroll
  for (int i = 0; i < 16; ++i) {
    int r = i * 4 + ty;
    s[r][tx] = f2bf(W[(size_t)(k0 + r) * 512 + n0 + tx]);
  }
  __syncthreads();
  const int nbase = mat * 512 + n0;
#pragma unroll
  for (int i = 0; i < 16; ++i) {
    int r = i * 4 + ty;
    Wt[(size_t)(nbase + r) * 1024 + k0 + tx] = s[tx][r];
  }
}

// ---------------------------------------------------------------------------
// Kernel 1: h1 = relu(x @ W1 + b1)  (RAW x) -> bf16 [8192,1024]
// ---------------------------------------------------------------------------
__global__ __launch_bounds__(256) void k_h1(const float* __restrict__ x,
                                            const float* __restrict__ W1,
                                            const float* __restrict__ b1,
                                            u16* __restrict__ h1) {
  const int row = blockIdx.x;
  const int c4  = threadIdx.x * 4;
  const float* xr = x + (size_t)row * 8;
  f32x4 acc = *(const f32x4*)(b1 + c4);
#pragma unroll
  for (int f = 0; f < 8; ++f) {
    float xv = xr[f];                       // row-uniform -> scalar loads
    f32x4 wv = *(const f32x4*)(W1 + f * 1024 + c4);
#pragma unroll
    for (int e = 0; e < 4; ++e) acc[e] = fmaf(xv, wv[e], acc[e]);
  }
  u16x4 o;
#pragma unroll
  for (int e = 0; e < 4; ++e) o[e] = f2bf(fmaxf(acc[e], 0.f));
  *(u16x4*)(h1 + (size_t)row * 1024 + c4) = o;
}

// ---------------------------------------------------------------------------
// Kernel 2: X2 = relu(h1 @ [W21|W22] + bias) -> bf16 [8192,1024]
// MFMA 16x16x32, 128x128 tile, BK=32.
// Software pipeline: register prefetch (kt+2) + double-buffered LDS,
// ONE barrier per K-iteration. Loads issued right after the barrier drain
// at the NEXT barrier -> a full compute phase of latency hiding.
// ---------------------------------------------------------------------------
__global__ __launch_bounds__(256) void k_gemm(const u16* __restrict__ A,
                                              const u16* __restrict__ Bt,
                                              const float* __restrict__ b21,
                                              const float* __restrict__ b22,
                                              u16* __restrict__ X2) {
  constexpr int K  = 1024;
  constexpr int BK = 32;
  constexpr int NT = K / BK;          // 32 K-tiles
  __shared__ u16 As[2][128 * BK];
  __shared__ u16 Bs[2][128 * BK];

  const int t    = threadIdx.x;
  const int row0 = blockIdx.y * 128;
  const int col0 = blockIdx.x * 128;
  const int w    = t >> 6;
  const int lane = t & 63;
  const int wr   = w >> 1, wc = w & 1;      // 2x2 wave grid, 64x64 per wave
  const int lrow = lane & 15;
  const int lk   = (lane >> 4) * 8;

  // chunk c: row = c>>2, 16B k-chunk = c&3. Thread owns chunks t and 256+t.
  const int c0 = t, c1 = 256 + t;
  const u16* gA0 = A  + (size_t)(row0 + (c0 >> 2)) * K + (c0 & 3) * 8;
  const u16* gA1 = A  + (size_t)(row0 + (c1 >> 2)) * K + (c1 & 3) * 8;
  const u16* gB0 = Bt + (size_t)(col0 + (c0 >> 2)) * K + (c0 & 3) * 8;
  const u16* gB1 = Bt + (size_t)(col0 + (c1 >> 2)) * K + (c1 & 3) * 8;
  const int lo0 = c0 * 8, lo1 = c1 * 8;

  f32x4 acc[4][4];
#pragma unroll
  for (int i = 0; i < 4; ++i)
#pragma unroll
    for (int j = 0; j < 4; ++j) acc[i][j] = f32x4{0.f, 0.f, 0.f, 0.f};

  // ---- prologue: tile0 -> buf0 ; tile1 -> regs ----
  {
    u16x8 ta0 = *(const u16x8*)gA0;
    u16x8 ta1 = *(const u16x8*)gA1;
    u16x8 tb0 = *(const u16x8*)gB0;
    u16x8 tb1 = *(const u16x8*)gB1;
    *(u16x8*)(As[0] + lo0) = ta0;
    *(u16x8*)(As[0] + lo1) = ta1;
    *(u16x8*)(Bs[0] + lo0) = tb0;
    *(u16x8*)(Bs[0] + lo1) = tb1;
  }
  u16x8 na0 = *(const u16x8*)(gA0 + BK);
  u16x8 na1 = *(const u16x8*)(gA1 + BK);
  u16x8 nb0 = *(const u16x8*)(gB0 + BK);
  u16x8 nb1 = *(const u16x8*)(gB1 + BK);

  for (int kt = 0; kt < NT; ++kt) {
    const int cur = kt & 1, nxt = cur ^ 1;
    __syncthreads();          // buf[cur] writes visible; drains prior prefetch

    // issue loads for tile kt+2 (drain at NEXT barrier -> hidden by compute)
    const int koff = (kt + 2 < NT ? kt + 2 : NT - 1) * BK;
    u16x8 fa0 = *(const u16x8*)(gA0 + koff);
    u16x8 fa1 = *(const u16x8*)(gA1 + koff);
    u16x8 fb0 = *(const u16x8*)(gB0 + koff);
    u16x8 fb1 = *(const u16x8*)(gB1 + koff);

    // compute from buf[cur]
    bf16x8 af[4], bfr[4];
#pragma unroll
    for (int i = 0; i < 4; ++i)
      af[i] = __builtin_bit_cast(bf16x8,
          *(const u16x8*)(As[cur] + (wr * 64 + i * 16 + lrow) * BK + lk));
#pragma unroll
    for (int j = 0; j < 4; ++j)
      bfr[j] = __builtin_bit_cast(bf16x8,
          *(const u16x8*)(Bs[cur] + (wc * 64 + j * 16 + lrow) * BK + lk));
#pragma unroll
    for (int i = 0; i < 4; ++i)
#pragma unroll
      for (int j = 0; j < 4; ++j)
        acc[i][j] = __builtin_amdgcn_mfma_f32_16x16x32_bf16(af[i], bfr[j], acc[i][j], 0, 0, 0);

    // stage tile kt+1 (already in regs, drained by this iter's barrier) -> buf[nxt]
    if (kt + 1 < NT) {
      *(u16x8*)(As[nxt] + lo0) = na0;
      *(u16x8*)(As[nxt] + lo1) = na1;
      *(u16x8*)(Bs[nxt] + lo0) = nb0;
      *(u16x8*)(Bs[nxt] + lo1) = nb1;
    }
    na0 = fa0; na1 = fa1; nb0 = fb0; nb1 = fb1;
  }

  // epilogue: D[row=(lane>>4)*4+rr][col=lane&15] + bias, relu, bf16 store
#pragma unroll
  for (int j = 0; j < 4; ++j) {
    int col = col0 + wc * 64 + j * 16 + lrow;
    float bias = (col < 512) ? b21[col] : b22[col - 512];
#pragma unroll
    for (int i = 0; i < 4; ++i) {
      int rbase = row0 + wr * 64 + i * 16 + (lane >> 4) * 4;
#pragma unroll
      for (int rr = 0; rr < 4; ++rr) {
        float v = acc[i][j][rr] + bias;
        X2[(size_t)(rbase + rr) * 1024 + col] = f2bf(fmaxf(v, 0.f));
      }
    }
  }
}

// ---------------------------------------------------------------------------
// Kernel 3: head dots. One wave per row; coalesced X2 reads; butterfly reduce.
// ---------------------------------------------------------------------------
__global__ __launch_bounds__(256) void k_head(const u16* __restrict__ X2,
                                              const float* __restrict__ W31,
                                              const float* __restrict__ W32,
                                              float* __restrict__ head) {
  const int wv   = threadIdx.x >> 6;
  const int lane = threadIdx.x & 63;
  const int r    = blockIdx.x * 4 + wv;
  const u16* row = X2 + (size_t)r * 1024;

  u16x8 v0 = *(const u16x8*)(row + lane * 8);          // x21 half
  u16x8 v1 = *(const u16x8*)(row + 512 + lane * 8);    // x22 half
  const f32x4* w31p = (const f32x4*)(W31 + lane * 16);
  const f32x4* w32p = (const f32x4*)(W32 + lane * 16);

  float a0x = 0.f, a0y = 0.f, a1x = 0.f, a1y = 0.f;
#pragma unroll
  for (int i = 0; i < 4; ++i) {
    f32x4 wa = w31p[i];
    float e0 = bf2f(v0[2 * i]), e1 = bf2f(v0[2 * i + 1]);
    a0x = fmaf(e0, wa[0], a0x); a0y = fmaf(e0, wa[1], a0y);
    a0x = fmaf(e1, wa[2], a0x); a0y = fmaf(e1, wa[3], a0y);
    f32x4 wb = w32p[i];
    float f0 = bf2f(v1[2 * i]), f1 = bf2f(v1[2 * i + 1]);
    a1x = fmaf(f0, wb[0], a1x); a1y = fmaf(f0, wb[1], a1y);
    a1x = fmaf(f1, wb[2], a1x); a1y = fmaf(f1, wb[3], a1y);
  }
#pragma unroll
  for (int m = 32; m >= 1; m >>= 1) {
    a0x += __shfl_xor(a0x, m, 64);
    a0y += __shfl_xor(a0y, m, 64);
    a1x += __shfl_xor(a1x, m, 64);
    a1y += __shfl_xor(a1y, m, 64);
  }
  if (lane == 0)
    *(f32x4*)(head + 4 * (size_t)r) = f32x4{a0x, a0y, a1x, a1y};
}

// ---------------------------------------------------------------------------
// Kernel 4: rank-2 dual PGD QP. One thread per row; heads precomputed.
// ---------------------------------------------------------------------------
__global__ __launch_bounds__(64) void k_qp(const float* __restrict__ x,
                                           const float* __restrict__ mean_,
                                           const float* __restrict__ std_,
                                           const float* __restrict__ head,
                                           const float* __restrict__ b31,
                                           const float* __restrict__ b32,
                                           const float* __restrict__ obstacles,
                                           float* __restrict__ out) {
  const int r = blockIdx.x * 64 + threadIdx.x;
  f32x4 hd = *(const f32x4*)(head + 4 * (size_t)r);
  float p0  = hd[0] + b31[0];
  float p1v = hd[1] + b31[1];
  float pp1 = 4.f / (1.f + expf(-(hd[2] + b32[0])));
  float pp2 = 4.f / (1.f + expf(-(hd[3] + b32[1])));

  const f32x4* xp = (const f32x4*)(x + (size_t)r * 8);
  f32x4 xa = xp[0], xb = xp[1];
  float px = xa[0] * std_[0] + mean_[0];
  float py = xa[1] * std_[1] + mean_[1];
  float th = xa[2] * std_[2] + mean_[2];
  float v  = xa[3] * std_[3] + mean_[3];
  float ax = xb[0] * std_[4] + mean_[4];
  float ay = xb[1] * std_[5] + mean_[5];
  float st = sinf(th), ct = cosf(th);
  float Lf2b = 2.f * v * v;

  float G0[9], G1[9], q[9];
  float s00 = 0.f, s01 = 0.f, s11 = 0.f;
#pragma unroll
  for (int m = 0; m < 9; ++m) {
    float ox, oy, orad;
    if (m < 8) {
      ox = obstacles[m * 3]; oy = obstacles[m * 3 + 1]; orad = obstacles[m * 3 + 2];
    } else { ox = ax; oy = ay; orad = 0.5f; }
    float R  = 0.6f + orad;                  // AGENT_RADIUS + orad + SAFETY
    float dx = px - ox, dy = py - oy;
    float bar  = dx * dx + dy * dy - R * R;
    float dct  = dx * ct + dy * st;
    float bdot = 2.f * v * dct;
    float g0 = 2.f * v * (dx * st - dy * ct);   // -LgLfbu1
    float g1 = -2.f * dct;                      // -LgLfbu2
    float h  = Lf2b + (pp1 + pp2) * bdot + pp1 * pp2 * bar;
    G0[m] = g0; G1[m] = g1;
    q[m] = g0 * p0 + g1 * p1v + h;
    s00 += g0 * g0; s01 += g0 * g1; s11 += g1 * g1;
  }
  float L = sqrtf(s00 * s00 + 2.f * s01 * s01 + s11 * s11) + 1e-6f;
  float alpha = 1.f / L;

  float lam[9];
#pragma unroll
  for (int m = 0; m < 9; ++m) lam[m] = 0.f;
  for (int it = 0; it < 300; ++it) {
    float pr0[9], pr1[9];
#pragma unroll
    for (int m = 0; m < 9; ++m) { pr0[m] = G0[m] * lam[m]; pr1[m] = G1[m] * lam[m]; }
    float t0 = (((pr0[0] + pr0[1]) + (pr0[2] + pr0[3])) +
                ((pr0[4] + pr0[5]) + (pr0[6] + pr0[7]))) + pr0[8];
    float t1 = (((pr1[0] + pr1[1]) + (pr1[2] + pr1[3])) +
                ((pr1[4] + pr1[5]) + (pr1[6] + pr1[7]))) + pr1[8];
#pragma unroll
    for (int m = 0; m < 9; ++m) {
      float g = fmaf(G0[m], t0, fmaf(G1[m], t1, q[m]));
      lam[m] = fmaxf(fmaf(-alpha, g, lam[m]), 0.f);
    }
  }
  float u0 = -p0, u1 = -p1v;
#pragma unroll
  for (int m = 0; m < 9; ++m) { u0 = fmaf(-G0[m], lam[m], u0); u1 = fmaf(-G1[m], lam[m], u1); }
  *(f32x2*)(out + 2 * (size_t)r) = f32x2{u0, u1};
}

// ---------------------------------------------------------------------------
extern "C" void kernel_launch(void* const* d_in, const int* in_sizes, int n_in,
                              void* d_out, int out_size, void* d_ws, size_t ws_size,
                              hipStream_t stream) {
  const float* x    = (const float*)d_in[0];
  const float* mean_= (const float*)d_in[1];
  const float* std_ = (const float*)d_in[2];
  const float* W1   = (const float*)d_in[3];
  const float* b1   = (const float*)d_in[4];
  const float* W21  = (const float*)d_in[5];
  const float* b21  = (const float*)d_in[6];
  const float* W22  = (const float*)d_in[7];
  const float* b22  = (const float*)d_in[8];
  // d_in[9],[10] = W23,b23 : dead code in reference (x33 unused)
  const float* W31  = (const float*)d_in[11];
  const float* b31  = (const float*)d_in[12];
  const float* W32  = (const float*)d_in[13];
  const float* b32  = (const float*)d_in[14];
  // d_in[15],[16] = W33,b33 : dead code
  const float* obst = (const float*)d_in[17];
  float* out = (float*)d_out;

  char* ws = (char*)d_ws;
  u16*   Wt   = (u16*)ws;                                             // 2 MB
  u16*   h1   = (u16*)(ws + (size_t)(1 << 21));                       // 16 MB
  u16*   X2   = (u16*)(ws + (size_t)(1 << 21) + (size_t)(1 << 24));   // 16 MB
  float* head = (float*)(ws + (size_t)(1 << 21) + 2 * (size_t)(1 << 24)); // 128 KB

  k_tr  <<<256, 256, 0, stream>>>(W21, W22, Wt);
  k_h1  <<<8192, 256, 0, stream>>>(x, W1, b1, h1);
  k_gemm<<<dim3(8, 64), 256, 0, stream>>>(h1, Wt, b21, b22, X2);
  k_head<<<2048, 256, 0, stream>>>(X2, W31, W32, head);
  k_qp  <<<128, 64, 0, stream>>>(x, mean_, std_, head, b31, b32, obst, out);
}